// Round 3
// baseline (113.526 us; speedup 1.0000x reference)
//
#include <hip/hip_runtime.h>

// out[b,k] = (WHT_2048(concat(x1[b],x2[b]))[k])^2 / 2048
// 2 rows per wave: 32 lanes per row, 64 floats per lane.
// k = ro*128 + l5*4 + ri   (ro in [0,16), l5 = lane&31, ri in [0,4))
//   reg index j = ro*4+ri  -> k bits {0,1,7,8,9,10} = j bits {0,1,2,3,4,5}
//     -> 6 in-register WHT stages, masks 1..32 on j
//   l5 -> k bits {2..6}
//     -> xor1,2,4,8 via DPP (pure VALU), xor16 via ds_swizzle (32-lane groups)
// No bpermute, no LDS arrays, no __syncthreads.

template <int CTRL>
__device__ __forceinline__ float dpp_xmov(float x) {
    return __int_as_float(__builtin_amdgcn_update_dpp(
        0, __float_as_int(x), CTRL, 0xF, 0xF, true));
}

__global__ __launch_bounds__(256) void qf_wht_kernel(const float* __restrict__ x1,
                                                     const float* __restrict__ x2,
                                                     float* __restrict__ out,
                                                     int nrows) {
    const int wave = threadIdx.x >> 6;
    const int lane = threadIdx.x & 63;
    const int half = lane >> 5;          // which of the wave's 2 rows
    const int l5   = lane & 31;          // lane within row
    const int row  = blockIdx.x * 8 + wave * 2 + half;
    if (row >= nrows) return;

    float v[64];

    // ---- load: float4 per lane; k<1024 from x1 (ro 0..7), k>=1024 from x2 (ro 8..15) ----
    const float* __restrict__ p1 = x1 + (size_t)row * 1024 + l5 * 4;
    const float* __restrict__ p2 = x2 + (size_t)row * 1024 + l5 * 4;
#pragma unroll
    for (int ro = 0; ro < 8; ++ro) {
        float4 f = *(const float4*)(p1 + ro * 128);
        v[ro * 4 + 0] = f.x; v[ro * 4 + 1] = f.y;
        v[ro * 4 + 2] = f.z; v[ro * 4 + 3] = f.w;
    }
#pragma unroll
    for (int ro = 8; ro < 16; ++ro) {
        float4 f = *(const float4*)(p2 + (ro - 8) * 128);
        v[ro * 4 + 0] = f.x; v[ro * 4 + 1] = f.y;
        v[ro * 4 + 2] = f.z; v[ro * 4 + 3] = f.w;
    }

    // ---- 6 in-register WHT stages over j (k bits 0,1,7,8,9,10) ----
#pragma unroll
    for (int m = 1; m < 64; m <<= 1) {
#pragma unroll
        for (int j = 0; j < 64; ++j) {
            if ((j & m) == 0) {
                const float a = v[j];
                const float b = v[j | m];
                v[j]     = a + b;
                v[j | m] = a - b;
            }
        }
    }

    // ---- 5 cross-lane stages over l5 (k bits 2..6): v' = s*v + partner ----
    // xor1: quad_perm [1,0,3,2]
    {
        const float s = (lane & 1) ? -1.0f : 1.0f;
#pragma unroll
        for (int j = 0; j < 64; ++j) {
            const float p = dpp_xmov<0xB1>(v[j]);
            v[j] = fmaf(s, v[j], p);
        }
    }
    // xor2: quad_perm [2,3,0,1]
    {
        const float s = (lane & 2) ? -1.0f : 1.0f;
#pragma unroll
        for (int j = 0; j < 64; ++j) {
            const float p = dpp_xmov<0x4E>(v[j]);
            v[j] = fmaf(s, v[j], p);
        }
    }
    // xor4 = xor3 (quad_perm [3,2,1,0]) ∘ xor7 (row_half_mirror)
    {
        const float s = (lane & 4) ? -1.0f : 1.0f;
#pragma unroll
        for (int j = 0; j < 64; ++j) {
            const float p = dpp_xmov<0x141>(dpp_xmov<0x1B>(v[j]));
            v[j] = fmaf(s, v[j], p);
        }
    }
    // xor8 = xor7 (row_half_mirror) ∘ xor15 (row_mirror)
    {
        const float s = (lane & 8) ? -1.0f : 1.0f;
#pragma unroll
        for (int j = 0; j < 64; ++j) {
            const float p = dpp_xmov<0x140>(dpp_xmov<0x141>(v[j]));
            v[j] = fmaf(s, v[j], p);
        }
    }
    // xor16: ds_swizzle BitMode xor_mask=16 (confined to 32-lane groups)
    {
        const float s = (lane & 16) ? -1.0f : 1.0f;
#pragma unroll
        for (int j = 0; j < 64; ++j) {
            const float p = __int_as_float(
                __builtin_amdgcn_ds_swizzle(__float_as_int(v[j]), 0x401F));
            v[j] = fmaf(s, v[j], p);
        }
    }

    // ---- square, scale, coalesced float4 stores ----
    const float c = 0.022097086912079608f;   // 1/sqrt(2048)
    float* __restrict__ po = out + (size_t)row * 2048 + l5 * 4;
#pragma unroll
    for (int ro = 0; ro < 16; ++ro) {
        float4 f;
        float t0 = v[ro * 4 + 0] * c, t1 = v[ro * 4 + 1] * c;
        float t2 = v[ro * 4 + 2] * c, t3 = v[ro * 4 + 3] * c;
        f.x = t0 * t0; f.y = t1 * t1; f.z = t2 * t2; f.w = t3 * t3;
        *(float4*)(po + ro * 128) = f;
    }
}

extern "C" void kernel_launch(void* const* d_in, const int* in_sizes, int n_in,
                              void* d_out, int out_size, void* d_ws, size_t ws_size,
                              hipStream_t stream) {
    const float* x1 = (const float*)d_in[0];
    const float* x2 = (const float*)d_in[1];
    float* out = (float*)d_out;

    const int nrows = in_sizes[0] / 1024;           // 8192
    const int blocks = (nrows + 7) / 8;             // 8 rows per 256-thread block
    qf_wht_kernel<<<blocks, 256, 0, stream>>>(x1, x2, out, nrows);
}

// Round 4
// 112.112 us; speedup vs baseline: 1.0126x; 1.0126x over previous
//
#include <hip/hip_runtime.h>

// out[b,k] = (WHT_2048(concat(x1[b],x2[b]))[k])^2 / 2048
// One wave (64 lanes) per row; 32 floats per lane (R2 layout — best occupancy).
// k = jo*256 + lane*4 + ji  (jo in [0,8), ji in [0,4))
//   k bits {0,1}   = ji   -> in-register stages
//   k bits {2..7}  = lane -> cross-lane: DPP (xor1,2,4,8), permlane16_swap (xor16),
//                            permlane32_swap (xor32) — ZERO LDS-pipe ops.
//   k bits {8,9,10}= jo   -> in-register stages

template <int CTRL>
__device__ __forceinline__ float dpp_xmov(float x) {
    return __int_as_float(__builtin_amdgcn_update_dpp(
        0, __float_as_int(x), CTRL, 0xF, 0xF, true));
}

typedef int int2v __attribute__((ext_vector_type(2)));

__global__ __launch_bounds__(256) void qf_wht_kernel(const float* __restrict__ x1,
                                                     const float* __restrict__ x2,
                                                     float* __restrict__ out,
                                                     int nrows) {
    const int wave = threadIdx.x >> 6;
    const int lane = threadIdx.x & 63;
    const int row  = blockIdx.x * 4 + wave;
    if (row >= nrows) return;

    float v[32];

    // ---- load: coalesced float4 ----
    const float* __restrict__ p1 = x1 + (size_t)row * 1024 + lane * 4;
    const float* __restrict__ p2 = x2 + (size_t)row * 1024 + lane * 4;
#pragma unroll
    for (int jo = 0; jo < 4; ++jo) {
        float4 f = *(const float4*)(p1 + jo * 256);
        v[jo * 4 + 0] = f.x; v[jo * 4 + 1] = f.y;
        v[jo * 4 + 2] = f.z; v[jo * 4 + 3] = f.w;
    }
#pragma unroll
    for (int jo = 4; jo < 8; ++jo) {
        float4 f = *(const float4*)(p2 + (jo - 4) * 256);
        v[jo * 4 + 0] = f.x; v[jo * 4 + 1] = f.y;
        v[jo * 4 + 2] = f.z; v[jo * 4 + 3] = f.w;
    }

    // ---- 5 in-register stages (k bits 0,1,8,9,10) ----
#pragma unroll
    for (int m = 1; m < 32; m <<= 1) {
#pragma unroll
        for (int j = 0; j < 32; ++j) {
            if ((j & m) == 0) {
                const float a = v[j];
                const float b = v[j | m];
                v[j]     = a + b;
                v[j | m] = a - b;
            }
        }
    }

    // ---- cross-lane stages (k bits 2..7) ----
    // xor1: quad_perm [1,0,3,2]
    {
        const float s = (lane & 1) ? -1.0f : 1.0f;
#pragma unroll
        for (int j = 0; j < 32; ++j) {
            const float p = dpp_xmov<0xB1>(v[j]);
            v[j] = fmaf(s, v[j], p);
        }
    }
    // xor2: quad_perm [2,3,0,1]
    {
        const float s = (lane & 2) ? -1.0f : 1.0f;
#pragma unroll
        for (int j = 0; j < 32; ++j) {
            const float p = dpp_xmov<0x4E>(v[j]);
            v[j] = fmaf(s, v[j], p);
        }
    }
    // xor4 = xor3 (quad_perm [3,2,1,0]) ∘ xor7 (row_half_mirror)
    {
        const float s = (lane & 4) ? -1.0f : 1.0f;
#pragma unroll
        for (int j = 0; j < 32; ++j) {
            const float p = dpp_xmov<0x141>(dpp_xmov<0x1B>(v[j]));
            v[j] = fmaf(s, v[j], p);
        }
    }
    // xor8 = xor7 (row_half_mirror) ∘ xor15 (row_mirror)
    {
        const float s = (lane & 8) ? -1.0f : 1.0f;
#pragma unroll
        for (int j = 0; j < 32; ++j) {
            const float p = dpp_xmov<0x140>(dpp_xmov<0x141>(v[j]));
            v[j] = fmaf(s, v[j], p);
        }
    }
    // xor16: v_permlane16_swap_b32 (pure VALU).
    // With a=b=v: per 32-lane group new_a={v_lo16,v_lo16}, new_b={v_hi16,v_hi16}.
    // Butterfly: v' = new_a + s16*new_b  (low lanes v+p, high lanes p-v).
    {
        const float s16 = (lane & 16) ? -1.0f : 1.0f;
#pragma unroll
        for (int j = 0; j < 32; ++j) {
            const int x = __float_as_int(v[j]);
            int2v r = __builtin_amdgcn_permlane16_swap(x, x, false, false);
            v[j] = fmaf(s16, __int_as_float(r.y), __int_as_float(r.x));
        }
    }
    // xor32: v_permlane32_swap_b32 (pure VALU).
    // With a=b=v: new_a={v_lo,v_lo}, new_b={v_hi,v_hi}; v' = new_a + s32*new_b.
    {
        const float s32 = (lane & 32) ? -1.0f : 1.0f;
#pragma unroll
        for (int j = 0; j < 32; ++j) {
            const int x = __float_as_int(v[j]);
            int2v r = __builtin_amdgcn_permlane32_swap(x, x, false, false);
            v[j] = fmaf(s32, __int_as_float(r.y), __int_as_float(r.x));
        }
    }

    // ---- square, scale, coalesced float4 stores ----
    const float c = 0.022097086912079608f;   // 1/sqrt(2048)
    float* __restrict__ po = out + (size_t)row * 2048 + lane * 4;
#pragma unroll
    for (int jo = 0; jo < 8; ++jo) {
        float4 f;
        float t0 = v[jo * 4 + 0] * c, t1 = v[jo * 4 + 1] * c;
        float t2 = v[jo * 4 + 2] * c, t3 = v[jo * 4 + 3] * c;
        f.x = t0 * t0; f.y = t1 * t1; f.z = t2 * t2; f.w = t3 * t3;
        *(float4*)(po + jo * 256) = f;
    }
}

extern "C" void kernel_launch(void* const* d_in, const int* in_sizes, int n_in,
                              void* d_out, int out_size, void* d_ws, size_t ws_size,
                              hipStream_t stream) {
    const float* x1 = (const float*)d_in[0];
    const float* x2 = (const float*)d_in[1];
    float* out = (float*)d_out;

    const int nrows = in_sizes[0] / 1024;           // 8192
    const int blocks = (nrows + 3) / 4;             // 4 rows per 256-thread block
    qf_wht_kernel<<<blocks, 256, 0, stream>>>(x1, x2, out, nrows);
}